// Round 12
// baseline (306.600 us; speedup 1.0000x reference)
//
#include <hip/hip_runtime.h>
#include <hip/hip_bf16.h>

typedef _Float16 half8 __attribute__((ext_vector_type(8)));
typedef _Float16 half4v __attribute__((ext_vector_type(4)));
typedef float f32x4 __attribute__((ext_vector_type(4)));

#define DEV static __device__ __forceinline__

// Problem constants: B=4, T=1024, D=1024, H=16, HD=64, TP=1024, SKV=2048

typedef __attribute__((address_space(1))) const unsigned int* gas_p;
typedef __attribute__((address_space(3))) unsigned int* las_p;
DEV void glds16(const void* g, void* s) {
  __builtin_amdgcn_global_load_lds((gas_p)g, (las_p)s, 16, 0, 0);
}
DEV void nt_store4(float* p, f32x4 v) {
  __builtin_nontemporal_store(v, (f32x4*)p);
}

// ---------------------------------------------------------------------------
// Fused weight prep + LN1.
// blocks [0,768): qkv prep (N=3072); [768,1024): merge; [1024,1280): ln1 w;
// blocks [1280,5376): LayerNorm1 rows (fp32 x -> f16 xn).
__global__ __launch_bounds__(256) void prep_ln(const float* __restrict__ qkv_wt,
                                               const float* __restrict__ qkv_mt,
                                               const float* __restrict__ mg_wt,
                                               const float* __restrict__ mg_mt,
                                               const float* __restrict__ l1_wt,
                                               const float* __restrict__ l1_mt,
                                               _Float16* __restrict__ wq,
                                               _Float16* __restrict__ wm,
                                               _Float16* __restrict__ wl,
                                               const float* __restrict__ x,
                                               const float* __restrict__ g1,
                                               const float* __restrict__ b1,
                                               _Float16* __restrict__ xn) {
  __shared__ float tile[64][65];
  if (blockIdx.x >= 1280) {  // ---- LN1 path
    float* red = &tile[0][0];
    const int row = blockIdx.x - 1280, tid = threadIdx.x, l = tid & 63, w = tid >> 6;
    float4 v = *(const float4*)(x + (long)row * 1024 + tid * 4);
    float s = v.x + v.y + v.z + v.w;
#pragma unroll
    for (int o = 32; o > 0; o >>= 1) s += __shfl_down(s, o, 64);
    if (l == 0) red[w] = s;
    __syncthreads();
    const float mu = (red[0] + red[1] + red[2] + red[3]) * (1.f / 1024.f);
    float dx = v.x - mu, dy = v.y - mu, dz = v.z - mu, dw = v.w - mu;
    float ss = dx * dx + dy * dy + dz * dz + dw * dw;
#pragma unroll
    for (int o = 32; o > 0; o >>= 1) ss += __shfl_down(ss, o, 64);
    __syncthreads();
    if (l == 0) red[w] = ss;
    __syncthreads();
    const float var = (red[0] + red[1] + red[2] + red[3]) * (1.f / 1024.f);
    const float rs = rsqrtf(var + 1e-3f);
    float4 gv = *(const float4*)(g1 + tid * 4);
    float4 bv = *(const float4*)(b1 + tid * 4);
    half4v o = {(_Float16)(dx * rs * gv.x + bv.x), (_Float16)(dy * rs * gv.y + bv.y),
                (_Float16)(dz * rs * gv.z + bv.z), (_Float16)(dw * rs * gv.w + bv.w)};
    *(half4v*)(xn + (long)row * 1024 + tid * 4) = o;
    return;
  }
  // ---- weight prep path
  const float *wt, *mt;
  _Float16* out;
  int N, bid;
  if (blockIdx.x < 768) {
    wt = qkv_wt; mt = qkv_mt; out = wq; N = 3072; bid = blockIdx.x;
  } else if (blockIdx.x < 1024) {
    wt = mg_wt; mt = mg_mt; out = wm; N = 1024; bid = blockIdx.x - 768;
  } else {
    wt = l1_wt; mt = l1_mt; out = wl; N = 1024; bid = blockIdx.x - 1024;
  }
  const int ntiles = N >> 6;
  const int nt = bid % ntiles, kt = bid / ntiles;
  const int k0 = kt << 6, n0 = nt << 6;
  const int t = threadIdx.x, r = t >> 2, c0 = (t & 3) << 4;
  const long ibase = (long)(k0 + r) * N + n0 + c0;
#pragma unroll
  for (int j = 0; j < 16; j += 4) {
    float4 a = *(const float4*)(wt + ibase + j);
    float4 b = *(const float4*)(mt + ibase + j);
    tile[r][c0 + j + 0] = tanhf(a.x) / (1.f + __expf(-b.x));
    tile[r][c0 + j + 1] = tanhf(a.y) / (1.f + __expf(-b.y));
    tile[r][c0 + j + 2] = tanhf(a.z) / (1.f + __expf(-b.z));
    tile[r][c0 + j + 3] = tanhf(a.w) / (1.f + __expf(-b.w));
  }
  __syncthreads();
  half8 o0, o1;
#pragma unroll
  for (int j = 0; j < 8; ++j) {
    o0[j] = (_Float16)tile[c0 + j][r];
    o1[j] = (_Float16)tile[c0 + 8 + j][r];
  }
  _Float16* dst = out + (long)(n0 + r) * 1024 + k0 + c0;
  *(half8*)dst = o0;
  *(half8*)(dst + 8) = o1;
}

// ---------------------------------------------------------------------------
// Fused KV prep (runs after QKV GEMM):
// blocks [0,4096): past k fp32 -> kful rows 0..1023 f16
// blocks [4096,6144): build v^T (B,H,64,2048) f16 from past v + vnew
__global__ __launch_bounds__(256) void kv_prep(const float* __restrict__ past,
                                               const _Float16* __restrict__ vnew,
                                               _Float16* __restrict__ kf,
                                               _Float16* __restrict__ vt) {
  __shared__ float tile[64][65];
  if (blockIdx.x < 4096) {
    const long e = ((long)blockIdx.x * 256 + threadIdx.x) * 4;
    const int b = (int)(e >> 20);
    const int rem = (int)(e & 1048575);
    float4 v = *(const float4*)(past + (long)b * 2097152 + rem);
    half4v o = {(_Float16)v.x, (_Float16)v.y, (_Float16)v.z, (_Float16)v.w};
    const int h = rem >> 16, td = rem & 65535;
    *(half4v*)(kf + (long)(b * 16 + h) * 131072 + td) = o;
    return;
  }
  const int bid = blockIdx.x - 4096;
  const int bh = bid >> 5, kt = bid & 31;
  const int b = bh >> 4, h = bh & 15;
  const int k0 = kt << 6;
  const int t = threadIdx.x, r = t >> 2, c0 = (t & 3) << 4;
  if (k0 < 1024) {
    const float* src = past + (((long)(b * 2 + 1) * 16 + h) * 1024 + (k0 + r)) * 64 + c0;
#pragma unroll
    for (int j = 0; j < 16; j += 4) {
      float4 v = *(const float4*)(src + j);
      tile[r][c0 + j + 0] = v.x;
      tile[r][c0 + j + 1] = v.y;
      tile[r][c0 + j + 2] = v.z;
      tile[r][c0 + j + 3] = v.w;
    }
  } else {
    const _Float16* src = vnew + ((long)bh * 1024 + (k0 - 1024 + r)) * 64 + c0;
    half8 a = *(const half8*)src;
    half8 bq = *(const half8*)(src + 8);
#pragma unroll
    for (int j = 0; j < 8; ++j) {
      tile[r][c0 + j] = (float)a[j];
      tile[r][c0 + 8 + j] = (float)bq[j];
    }
  }
  __syncthreads();
  half8 o0, o1;
#pragma unroll
  for (int j = 0; j < 8; ++j) {
    o0[j] = (_Float16)tile[c0 + j][r];
    o1[j] = (_Float16)tile[c0 + 8 + j][r];
  }
  _Float16* dst = vt + ((long)bh * 64 + r) * 2048 + k0 + c0;
  *(half8*)dst = o0;
  *(half8*)(dst + 8) = o1;
}

// ---------------------------------------------------------------------------
// LayerNorm row kernel (f16 in -> f16 out), used for LN2.
__global__ __launch_bounds__(256) void ln_k(const _Float16* __restrict__ xin,
                                            const float* __restrict__ g,
                                            const float* __restrict__ be,
                                            _Float16* __restrict__ out) {
  __shared__ float red[4];
  const int row = blockIdx.x, tid = threadIdx.x, l = tid & 63, w = tid >> 6;
  half4v v = *(const half4v*)(xin + (long)row * 1024 + tid * 4);
  float v0 = (float)v[0], v1 = (float)v[1], v2 = (float)v[2], v3 = (float)v[3];
  float s = v0 + v1 + v2 + v3;
#pragma unroll
  for (int o = 32; o > 0; o >>= 1) s += __shfl_down(s, o, 64);
  if (l == 0) red[w] = s;
  __syncthreads();
  const float mu = (red[0] + red[1] + red[2] + red[3]) * (1.f / 1024.f);
  float dx = v0 - mu, dy = v1 - mu, dz = v2 - mu, dw = v3 - mu;
  float ss = dx * dx + dy * dy + dz * dz + dw * dw;
#pragma unroll
  for (int o = 32; o > 0; o >>= 1) ss += __shfl_down(ss, o, 64);
  __syncthreads();
  if (l == 0) red[w] = ss;
  __syncthreads();
  const float var = (red[0] + red[1] + red[2] + red[3]) * (1.f / 1024.f);
  const float rs = rsqrtf(var + 1e-3f);
  float4 gv = *(const float4*)(g + tid * 4);
  float4 bv = *(const float4*)(be + tid * 4);
  half4v o = {(_Float16)(dx * rs * gv.x + bv.x), (_Float16)(dy * rs * gv.y + bv.y),
              (_Float16)(dz * rs * gv.z + bv.z), (_Float16)(dw * rs * gv.w + bv.w)};
  *(half4v*)(out + (long)row * 1024 + tid * 4) = o;
}

// ---------------------------------------------------------------------------
// GEMM BMxBN tile, BK=64, 256 threads (4 waves 2x2), K=1024, glds staging,
// DOUBLE-buffered LDS, 1 barrier per K-step (r8-proven structure).
// EPI 0: QKV scatter. EPI 1: out_f16 = res_f32 + acc. EPI 2: out_f32 = res_f16 + acc.
template <int BM, int BN, int EPI>
__global__ __launch_bounds__(256) void gemm_k(const _Float16* __restrict__ A,
                                              const _Float16* __restrict__ Bt,
                                              int mtiles,
                                              _Float16* __restrict__ e_q,
                                              _Float16* __restrict__ e_k,
                                              _Float16* __restrict__ e_v,
                                              float* __restrict__ e_present,
                                              const void* __restrict__ e_resv,
                                              void* __restrict__ e_outv) {
  constexpr int FM = BM / 32, FN = BN / 32;
  __shared__ __align__(16) char smem[2 * BM * 128 + 2 * BN * 128];
  char* Bbase = smem + 2 * BM * 128;
  const int tid = threadIdx.x, l = tid & 63, w = tid >> 6;
  const int wm = w >> 1, wn = w & 1;
  const int bm = blockIdx.x % mtiles, bn = blockIdx.x / mtiles;
  const long m0 = (long)bm * BM, n0 = (long)bn * BN;

  f32x4 acc[FM][FN];
#pragma unroll
  for (int i = 0; i < FM; ++i)
#pragma unroll
    for (int j = 0; j < FN; ++j) acc[i][j] = (f32x4){0.f, 0.f, 0.f, 0.f};

  auto stage = [&](int b, int kt) {
#pragma unroll
    for (int i = 0; i < FM; ++i) {
      const int cid = i * 256 + tid, row = cid >> 3, u = cid & 7;
      glds16(A + (m0 + row) * 1024 + kt * 64 + ((u ^ (row & 7)) << 3),
             smem + b * BM * 128 + i * 4096 + w * 1024);
    }
#pragma unroll
    for (int i = 0; i < FN; ++i) {
      const int cid = i * 256 + tid, row = cid >> 3, u = cid & 7;
      glds16(Bt + (n0 + row) * 1024 + kt * 64 + ((u ^ (row & 7)) << 3),
             Bbase + b * BN * 128 + i * 4096 + w * 1024);
    }
  };

  stage(0, 0);
  __syncthreads();
  for (int kt = 0; kt < 16; ++kt) {
    const int cur = kt & 1;
    if (kt < 15) stage(cur ^ 1, kt + 1);
    const char* As = smem + cur * BM * 128;
    const char* Bs = Bbase + cur * BN * 128;
    __builtin_amdgcn_s_setprio(1);
#pragma unroll
    for (int k2 = 0; k2 < 2; ++k2) {
      const int sl = k2 * 4 + (l >> 4);
      half8 bfr[FN];
#pragma unroll
      for (int fn = 0; fn < FN; ++fn) {
        const int rn = wn * (BN / 2) + fn * 16 + (l & 15);
        bfr[fn] = *(const half8*)(Bs + rn * 128 + ((sl ^ (rn & 7)) << 4));
      }
#pragma unroll
      for (int fm = 0; fm < FM; ++fm) {
        const int rm = wm * (BM / 2) + fm * 16 + (l & 15);
        const half8 afr = *(const half8*)(As + rm * 128 + ((sl ^ (rm & 7)) << 4));
#pragma unroll
        for (int fn = 0; fn < FN; ++fn)
          acc[fm][fn] = __builtin_amdgcn_mfma_f32_16x16x32_f16(afr, bfr[fn], acc[fm][fn], 0, 0, 0);
      }
    }
    __builtin_amdgcn_s_setprio(0);
    __syncthreads();
  }
#pragma unroll
  for (int fm = 0; fm < FM; ++fm) {
#pragma unroll
    for (int fn = 0; fn < FN; ++fn) {
#pragma unroll
      for (int r = 0; r < 4; ++r) {
        const long row = m0 + wm * (BM / 2) + fm * 16 + (l >> 4) * 4 + r;
        const long col = n0 + wn * (BN / 2) + fn * 16 + (l & 15);
        const float v = acc[fm][fn][r];
        if constexpr (EPI == 0) {
          const int b = (int)(row >> 10), t = (int)(row & 1023);
          const int sec = (int)(col >> 10), h = ((int)col >> 6) & 15, hd = (int)col & 63;
          const long bh = b * 16 + h;
          if (sec == 0) {
            e_q[(bh * 1024 + t) * 64 + hd] = (_Float16)v;
          } else if (sec == 1) {
            e_present[(((long)(b * 2) * 16 + h) * 1024 + t) * 64 + hd] = v;
            e_k[(bh * 2048 + 1024 + t) * 64 + hd] = (_Float16)v;
          } else {
            e_present[(((long)(b * 2 + 1) * 16 + h) * 1024 + t) * 64 + hd] = v;
            e_v[(bh * 1024 + t) * 64 + hd] = (_Float16)v;
          }
        } else if constexpr (EPI == 1) {
          ((_Float16*)e_outv)[row * 1024 + col] =
              (_Float16)(((const float*)e_resv)[row * 1024 + col] + v);
        } else {
          ((float*)e_outv)[row * 1024 + col] =
              (float)((const _Float16*)e_resv)[row * 1024 + col] + v;
        }
      }
    }
  }
}

// ---------------------------------------------------------------------------
// Fused attention (r8 structure + NT msk stores). Block = (b,h,q-tile-of-64);
// wave owns 16 q-rows. Phase 1: 128-col kv chunks, K dbuf. Phase 2: 64-col
// chunks, K+V dbuf, P via LDS ps tile. setprio on MFMA clusters.
// LDS 40 KB -> 4 blocks/CU. Swapped QK^T, no-max softmax, XCD-pinned.
__global__ __launch_bounds__(256, 4) void attn_k(const _Float16* __restrict__ qg,
                                                 const _Float16* __restrict__ kg,
                                                 const _Float16* __restrict__ vtg,
                                                 float* __restrict__ msk,
                                                 _Float16* __restrict__ ah) {
  __shared__ __align__(16) char smem[40960];
  char* ps_all = smem + 32768;
  const int tid = threadIdx.x, l = tid & 63, w = tid >> 6;
  char* psw = ps_all + w * 2048;  // wave-private [16 rows][128B]
  const int lq = l & 15, hi = l >> 4;

  // XCD-pinned decode: bh's 16 q-tiles all land on XCD (bh & 7)
  const int x = blockIdx.x & 7, g = blockIdx.x >> 3;
  const int bh = (g & 7) * 8 + x;
  const int qt = 15 - (g >> 3);  // heavy tiles first
  const int r0 = qt << 6;
  const int rowg0 = r0 + w * 16;  // this wave's first global q-row

  const _Float16* kb = kg + (long)bh * 131072;
  const _Float16* vb = vtg + (long)bh * 131072;
  float* mskb = msk + ((long)bh * 1024 + rowg0) * 2048;

  // Q fragments for this wave's 16 rows (row = lq, k = k2*32 + hi*8)
  half8 qa[2];
  {
    const _Float16* qp = qg + ((long)bh * 1024 + rowg0 + lq) * 64 + hi * 8;
    qa[0] = *(const half8*)qp;
    qa[1] = *(const half8*)(qp + 32);
  }

  constexpr float C1 = 0.125f * 1.44269504088896341f;  // 1/sqrt(64) * log2e
  const int lim = rowg0 + lq + 1024;  // causal: col <= lim for this lane's row

  // ---- phase 1: row sums of 2^(S*C1). 128-col chunks, K dbuf in 2x16KB.
  const int nc1 = (r0 + 1215) >> 7;
  auto stageK128 = [&](int b, int c) {
#pragma unroll
    for (int i = 0; i < 4; ++i) {
      const int cid = i * 256 + tid, row = cid >> 3, u = cid & 7;
      glds16(kb + (long)(c * 128 + row) * 64 + ((u ^ (row & 7)) << 3),
             smem + b * 16384 + i * 4096 + w * 1024);
    }
  };
  float rsum = 0.f;
  stageK128(0, 0);
  __syncthreads();
  for (int c = 0; c < nc1; ++c) {
    const int cur = c & 1;
    if (c + 1 < nc1) stageK128(cur ^ 1, c + 1);
    const char* ks = smem + cur * 16384;
    f32x4 sa[8];
#pragma unroll
    for (int fn = 0; fn < 8; ++fn) sa[fn] = (f32x4){0.f, 0.f, 0.f, 0.f};
    __builtin_amdgcn_s_setprio(1);
#pragma unroll
    for (int k2 = 0; k2 < 2; ++k2) {
      const int sl = k2 * 4 + hi;
      half8 ak[8];
#pragma unroll
      for (int fn = 0; fn < 8; ++fn) {
        const int rn = fn * 16 + lq;
        ak[fn] = *(const half8*)(ks + rn * 128 + ((sl ^ (rn & 7)) << 4));
      }
#pragma unroll
      for (int fn = 0; fn < 8; ++fn)
        sa[fn] = __builtin_amdgcn_mfma_f32_16x16x32_f16(ak[fn], qa[k2], sa[fn], 0, 0, 0);
    }
    __builtin_amdgcn_s_setprio(0);
    if (c < nc1 - 1) {
#pragma unroll
      for (int fn = 0; fn < 8; ++fn)
#pragma unroll
        for (int r = 0; r < 4; ++r) rsum += __builtin_amdgcn_exp2f(sa[fn][r] * C1);
    } else {
#pragma unroll
      for (int fn = 0; fn < 8; ++fn)
#pragma unroll
        for (int r = 0; r < 4; ++r) {
          const int col = c * 128 + fn * 16 + hi * 4 + r;
          const float e = __builtin_amdgcn_exp2f(sa[fn][r] * C1);
          rsum += (col <= lim) ? e : 0.f;
        }
    }
    __syncthreads();
  }
  // combine the 4 lanes (hi=0..3) sharing q-row lq
  rsum += __shfl_xor(rsum, 16, 64);
  rsum += __shfl_xor(rsum, 32, 64);
  const float c2s = -__builtin_amdgcn_logf(rsum);  // -log2(sum)

  // ---- phase 2: 64-col chunks; recompute S, p, msk(NT) + P(LDS) + PV
  const int nc = (r0 + 1151) >> 6;
  auto stageK = [&](int b, int c) {
#pragma unroll
    for (int i = 0; i < 2; ++i) {
      const int cid = i * 256 + tid, row = cid >> 3, u = cid & 7;
      glds16(kb + (long)(c * 64 + row) * 64 + ((u ^ (row & 7)) << 3),
             smem + b * 8192 + i * 4096 + w * 1024);
    }
  };
  auto stageV = [&](int b, int c) {
#pragma unroll
    for (int i = 0; i < 2; ++i) {
      const int cid = i * 256 + tid, row = cid >> 3, u = cid & 7;
      glds16(vb + (long)row * 2048 + c * 64 + ((u ^ (row & 7)) << 3),
             smem + 16384 + b * 8192 + i * 4096 + w * 1024);
    }
  };

  f32x4 pv[4];
#pragma unroll
  for (int j = 0; j < 4; ++j) pv[j] = (f32x4){0.f, 0.f, 0.f, 0.f};
  __syncthreads();  // phase-1 LDS reads done before phase-2 staging
  stageK(0, 0);
  stageV(0, 0);
  __syncthreads();
  for (int c = 0; c < nc; ++c) {
    const int cur = c & 1;
    if (c + 1 < nc) {
      stageK(cur ^ 1, c + 1);
      stageV(cur ^ 1, c + 1);
    }
    const char* ks = smem + cur * 8192;
    f32x4 sa[4];
#pragma unroll
    for (int fn = 0; fn < 4; ++fn) sa[fn] = (f32x4){0.f, 0.f, 0.f, 0.f};
    __builtin_amdgcn_s_setprio(1);
#pragma unroll
    for (int k2 = 0; k2 < 2; ++k2) {
      const int sl = k2 * 4 + hi;
      half8 ak[4];
#pragma unroll
      for (int fn = 0; fn < 4; ++fn) {
        const int rn = fn * 16 + lq;
        ak[fn] = *(const half8*)(ks + rn * 128 + ((sl ^ (rn & 7)) << 4));
      }
#pragma unroll
      for (int fn = 0; fn < 4; ++fn)
        sa[fn] = __builtin_amdgcn_mfma_f32_16x16x32_f16(ak[fn], qa[k2], sa[fn], 0, 0, 0);
    }
    __builtin_amdgcn_s_setprio(0);
    const bool bound = (c == nc - 1);
#pragma unroll
    for (int fn = 0; fn < 4; ++fn) {
      float pr[4];
#pragma unroll
      for (int r = 0; r < 4; ++r) {
        float p = __builtin_amdgcn_exp2f(sa[fn][r] * C1 + c2s);
        if (bound) {
          const int col = c * 64 + fn * 16 + hi * 4 + r;
          p = (col <= lim) ? p : 0.f;
        }
        pr[r] = p;
      }
      // msk: 16B NT store (msk never re-read; keep K/V resident in L2)
      nt_store4(mskb + (long)lq * 2048 + c * 64 + fn * 16 + hi * 4,
                (f32x4){pr[0], pr[1], pr[2], pr[3]});
      // P -> LDS f16 (swizzle-consistent with the b128 PV reads)
      const half4v hv = {(_Float16)pr[0], (_Float16)pr[1], (_Float16)pr[2],
                         (_Float16)pr[3]};
      const int bc = fn * 32 + hi * 8;  // byte col in [0,128)
      *(half4v*)(psw + lq * 128 + ((((bc >> 4) ^ (lq & 7)) << 4) | (bc & 15))) = hv;
    }
    __builtin_amdgcn_wave_barrier();
    asm volatile("s_waitcnt lgkmcnt(0)" ::: "memory");
    __builtin_amdgcn_sched_barrier(0);
    // PV: A = this wave's P rows, B = V^T rows from LDS
    const char* vs = smem + 16384 + cur * 8192;
    __builtin_amdgcn_s_setprio(1);
#pragma unroll
    for (int k2p = 0; k2p < 2; ++k2p) {
      const int sl2 = k2p * 4 + hi;
      const half8 pa = *(const half8*)(psw + lq * 128 + ((sl2 ^ (lq & 7)) << 4));
      half8 bv[4];
#pragma unroll
      for (int fn2 = 0; fn2 < 4; ++fn2) {
        const int rd = fn2 * 16 + lq;
        bv[fn2] = *(const half8*)(vs + rd * 128 + ((sl2 ^ (rd & 7)) << 4));
      }
#pragma unroll
      for (int fn2 = 0; fn2 < 4; ++fn2)
        pv[fn2] = __builtin_amdgcn_mfma_f32_16x16x32_f16(pa, bv[fn2], pv[fn2], 0, 0, 0);
    }
    __builtin_amdgcn_s_setprio(0);
    __syncthreads();
  }

  // zero-fill fully-masked tail columns (cols >= nc*64) for this wave's rows
  const int ntail = 512 - (nc << 4);  // float4s per row
  if (ntail > 0) {
    for (int row = 0; row < 16; ++row)
      for (int i = l; i < ntail; i += 64)
        nt_store4(mskb + (long)row * 2048 + nc * 64 + i * 4,
                  (f32x4){0.f, 0.f, 0.f, 0.f});
  }

  // attention output rows -> ah (B*T,1024) f16
  const int b_ = bh >> 4, h_ = bh & 15;
  _Float16* ahb = ah + ((long)b_ * 1024 + rowg0) * 1024 + h_ * 64;
#pragma unroll
  for (int fn2 = 0; fn2 < 4; ++fn2)
#pragma unroll
    for (int r = 0; r < 4; ++r)
      ahb[(long)(hi * 4 + r) * 1024 + fn2 * 16 + lq] = (_Float16)pv[fn2][r];
}

// ---------------------------------------------------------------------------
extern "C" void kernel_launch(void* const* d_in, const int* in_sizes, int n_in,
                              void* d_out, int out_size, void* d_ws, size_t ws_size,
                              hipStream_t stream) {
  const float* x = (const float*)d_in[0];
  const float* past = (const float*)d_in[1];
  const float* qkv_wt = (const float*)d_in[2];
  const float* qkv_mt = (const float*)d_in[3];
  const float* merge_wt = (const float*)d_in[4];
  const float* merge_mt = (const float*)d_in[5];
  const float* ln1_wt = (const float*)d_in[6];
  const float* ln1_mt = (const float*)d_in[7];
  const float* g1 = (const float*)d_in[8];
  const float* b1 = (const float*)d_in[9];
  const float* g2 = (const float*)d_in[10];
  const float* b2 = (const float*)d_in[11];

  float* out = (float*)d_out;
  float* o_xm = out;                       // (4,1024,1024)
  float* o_present = out + 4194304;        // (4,2,16,1024,64)
  float* o_msk = out + 4194304 + 8388608;  // (4,16,1024,2048)

  char* ws = (char*)d_ws;
  _Float16* wq_t = (_Float16*)(ws + 0);         // 3072x1024 f16
  _Float16* wm_t = (_Float16*)(ws + 6291456);   // 1024x1024 f16
  _Float16* wl_t = (_Float16*)(ws + 8388608);   // 1024x1024 f16
  _Float16* xn   = (_Float16*)(ws + 10485760);  // 4096x1024 f16
  _Float16* qws  = (_Float16*)(ws + 18874368);  // (4,16,1024,64)
  _Float16* kful = (_Float16*)(ws + 27262976);  // (4,16,2048,64)
  _Float16* vnew = (_Float16*)(ws + 44040192);  // (4,16,1024,64)
  _Float16* vt   = (_Float16*)(ws + 52428800);  // (4,16,64,2048)
  _Float16* ah   = (_Float16*)(ws + 69206016);  // 4096x1024 f16
  _Float16* xa   = (_Float16*)(ws + 77594624);  // 4096x1024 f16 (residual)

  prep_ln<<<5376, 256, 0, stream>>>(qkv_wt, qkv_mt, merge_wt, merge_mt, ln1_wt,
                                    ln1_mt, wq_t, wm_t, wl_t, x, g1, b1, xn);
  gemm_k<128, 128, 0><<<768, 256, 0, stream>>>(xn, wq_t, 32, qws, kful, vnew,
                                               o_present, nullptr, nullptr);
  kv_prep<<<6144, 256, 0, stream>>>(past, vnew, kful, vt);
  attn_k<<<1024, 256, 0, stream>>>(qws, kful, vt, o_msk, ah);
  gemm_k<64, 128, 1><<<512, 256, 0, stream>>>(ah, wm_t, 64, nullptr, nullptr,
                                              nullptr, nullptr, x, xa);
  ln_k<<<4096, 256, 0, stream>>>(xa, g2, b2, xn);
  gemm_k<64, 128, 2><<<512, 256, 0, stream>>>(xn, wl_t, 64, nullptr, nullptr,
                                              nullptr, nullptr, xa, o_xm);
}

// Round 13
// 289.492 us; speedup vs baseline: 1.0591x; 1.0591x over previous
//
#include <hip/hip_runtime.h>
#include <hip/hip_bf16.h>

typedef _Float16 half8 __attribute__((ext_vector_type(8)));
typedef _Float16 half4v __attribute__((ext_vector_type(4)));
typedef float f32x4 __attribute__((ext_vector_type(4)));

#define DEV static __device__ __forceinline__

// Problem constants: B=4, T=1024, D=1024, H=16, HD=64, TP=1024, SKV=2048

typedef __attribute__((address_space(1))) const unsigned int* gas_p;
typedef __attribute__((address_space(3))) unsigned int* las_p;
DEV void glds16(const void* g, void* s) {
  __builtin_amdgcn_global_load_lds((gas_p)g, (las_p)s, 16, 0, 0);
}

// ---------------------------------------------------------------------------
// Fused prep: weight prep + past-K conversion + past-V transpose (all of
// which depend only on inputs, not on the QKV GEMM).
// blocks [0,768): qkv w prep (N=3072); [768,1024): merge; [1024,1280): ln1 w;
// blocks [1280,5376): past k fp32 -> kful rows 0..1023 f16;
// blocks [5376,6400): v^T from past v (k0 < 1024).
__global__ __launch_bounds__(256) void prep_all(const float* __restrict__ qkv_wt,
                                                const float* __restrict__ qkv_mt,
                                                const float* __restrict__ mg_wt,
                                                const float* __restrict__ mg_mt,
                                                const float* __restrict__ l1_wt,
                                                const float* __restrict__ l1_mt,
                                                _Float16* __restrict__ wq,
                                                _Float16* __restrict__ wm,
                                                _Float16* __restrict__ wl,
                                                const float* __restrict__ past,
                                                _Float16* __restrict__ kf,
                                                _Float16* __restrict__ vt) {
  __shared__ float tile[64][65];
  if (blockIdx.x >= 1280 && blockIdx.x < 5376) {  // ---- past-K conversion
    const long e = ((long)(blockIdx.x - 1280) * 256 + threadIdx.x) * 4;
    const int b = (int)(e >> 20);
    const int rem = (int)(e & 1048575);
    float4 v = *(const float4*)(past + (long)b * 2097152 + rem);
    half4v o = {(_Float16)v.x, (_Float16)v.y, (_Float16)v.z, (_Float16)v.w};
    const int h = rem >> 16, td = rem & 65535;
    *(half4v*)(kf + (long)(b * 16 + h) * 131072 + td) = o;
    return;
  }
  if (blockIdx.x >= 5376) {  // ---- past-V transpose (k0 < 1024)
    const int bid = blockIdx.x - 5376;
    const int bh = bid >> 4, kt = bid & 15;
    const int b = bh >> 4, h = bh & 15;
    const int k0 = kt << 6;
    const int t = threadIdx.x, r = t >> 2, c0 = (t & 3) << 4;
    const float* src = past + (((long)(b * 2 + 1) * 16 + h) * 1024 + (k0 + r)) * 64 + c0;
#pragma unroll
    for (int j = 0; j < 16; j += 4) {
      float4 v = *(const float4*)(src + j);
      tile[r][c0 + j + 0] = v.x;
      tile[r][c0 + j + 1] = v.y;
      tile[r][c0 + j + 2] = v.z;
      tile[r][c0 + j + 3] = v.w;
    }
    __syncthreads();
    half8 o0, o1;
#pragma unroll
    for (int j = 0; j < 8; ++j) {
      o0[j] = (_Float16)tile[c0 + j][r];
      o1[j] = (_Float16)tile[c0 + 8 + j][r];
    }
    _Float16* dst = vt + ((long)bh * 64 + r) * 2048 + k0 + c0;
    *(half8*)dst = o0;
    *(half8*)(dst + 8) = o1;
    return;
  }
  // ---- weight prep path
  const float *wt, *mt;
  _Float16* out;
  int N, bid;
  if (blockIdx.x < 768) {
    wt = qkv_wt; mt = qkv_mt; out = wq; N = 3072; bid = blockIdx.x;
  } else if (blockIdx.x < 1024) {
    wt = mg_wt; mt = mg_mt; out = wm; N = 1024; bid = blockIdx.x - 768;
  } else {
    wt = l1_wt; mt = l1_mt; out = wl; N = 1024; bid = blockIdx.x - 1024;
  }
  const int ntiles = N >> 6;
  const int nt = bid % ntiles, kt = bid / ntiles;
  const int k0 = kt << 6, n0 = nt << 6;
  const int t = threadIdx.x, r = t >> 2, c0 = (t & 3) << 4;
  const long ibase = (long)(k0 + r) * N + n0 + c0;
#pragma unroll
  for (int j = 0; j < 16; j += 4) {
    float4 a = *(const float4*)(wt + ibase + j);
    float4 b = *(const float4*)(mt + ibase + j);
    tile[r][c0 + j + 0] = tanhf(a.x) / (1.f + __expf(-b.x));
    tile[r][c0 + j + 1] = tanhf(a.y) / (1.f + __expf(-b.y));
    tile[r][c0 + j + 2] = tanhf(a.z) / (1.f + __expf(-b.z));
    tile[r][c0 + j + 3] = tanhf(a.w) / (1.f + __expf(-b.w));
  }
  __syncthreads();
  half8 o0, o1;
#pragma unroll
  for (int j = 0; j < 8; ++j) {
    o0[j] = (_Float16)tile[c0 + j][r];
    o1[j] = (_Float16)tile[c0 + 8 + j][r];
  }
  _Float16* dst = out + (long)(n0 + r) * 1024 + k0 + c0;
  *(half8*)dst = o0;
  *(half8*)(dst + 8) = o1;
}

// ---------------------------------------------------------------------------
// Post-QKV v^T tail: k0 >= 1024 quarter of v^T, from vnew (GEMM output).
__global__ __launch_bounds__(256) void kv_late(const _Float16* __restrict__ vnew,
                                               _Float16* __restrict__ vt) {
  __shared__ float tile[64][65];
  const int bid = blockIdx.x;
  const int bh = bid >> 4, kt = 16 + (bid & 15);
  const int k0 = kt << 6;
  const int t = threadIdx.x, r = t >> 2, c0 = (t & 3) << 4;
  const _Float16* src = vnew + ((long)bh * 1024 + (k0 - 1024 + r)) * 64 + c0;
  half8 a = *(const half8*)src;
  half8 bq = *(const half8*)(src + 8);
#pragma unroll
  for (int j = 0; j < 8; ++j) {
    tile[r][c0 + j] = (float)a[j];
    tile[r][c0 + 8 + j] = (float)bq[j];
  }
  __syncthreads();
  half8 o0, o1;
#pragma unroll
  for (int j = 0; j < 8; ++j) {
    o0[j] = (_Float16)tile[c0 + j][r];
    o1[j] = (_Float16)tile[c0 + 8 + j][r];
  }
  _Float16* dst = vt + ((long)bh * 64 + r) * 2048 + k0 + c0;
  *(half8*)dst = o0;
  *(half8*)(dst + 8) = o1;
}

// ---------------------------------------------------------------------------
// LayerNorm row kernel: F16IN=0 fp32 in / F16IN=1 f16 in -> f16 out.
template <int F16IN>
__global__ __launch_bounds__(256) void ln_k(const void* __restrict__ xin,
                                            const float* __restrict__ g,
                                            const float* __restrict__ be,
                                            _Float16* __restrict__ out) {
  __shared__ float red[4];
  const int row = blockIdx.x, tid = threadIdx.x, l = tid & 63, w = tid >> 6;
  float v0, v1, v2, v3;
  if constexpr (F16IN == 0) {
    float4 v = *(const float4*)((const float*)xin + (long)row * 1024 + tid * 4);
    v0 = v.x; v1 = v.y; v2 = v.z; v3 = v.w;
  } else {
    half4v v = *(const half4v*)((const _Float16*)xin + (long)row * 1024 + tid * 4);
    v0 = (float)v[0]; v1 = (float)v[1]; v2 = (float)v[2]; v3 = (float)v[3];
  }
  float s = v0 + v1 + v2 + v3;
#pragma unroll
  for (int o = 32; o > 0; o >>= 1) s += __shfl_down(s, o, 64);
  if (l == 0) red[w] = s;
  __syncthreads();
  const float mu = (red[0] + red[1] + red[2] + red[3]) * (1.f / 1024.f);
  float dx = v0 - mu, dy = v1 - mu, dz = v2 - mu, dw = v3 - mu;
  float ss = dx * dx + dy * dy + dz * dz + dw * dw;
#pragma unroll
  for (int o = 32; o > 0; o >>= 1) ss += __shfl_down(ss, o, 64);
  __syncthreads();
  if (l == 0) red[w] = ss;
  __syncthreads();
  const float var = (red[0] + red[1] + red[2] + red[3]) * (1.f / 1024.f);
  const float rs = rsqrtf(var + 1e-3f);
  float4 gv = *(const float4*)(g + tid * 4);
  float4 bv = *(const float4*)(be + tid * 4);
  half4v o = {(_Float16)(dx * rs * gv.x + bv.x), (_Float16)(dy * rs * gv.y + bv.y),
              (_Float16)(dz * rs * gv.z + bv.z), (_Float16)(dw * rs * gv.w + bv.w)};
  *(half4v*)(out + (long)row * 1024 + tid * 4) = o;
}

// ---------------------------------------------------------------------------
// GEMM BMxBN tile, BK=64, 256 threads (4 waves 2x2), K=1024, glds staging,
// DOUBLE-buffered LDS, 1 barrier per K-step (r8-proven structure).
// EPI 0: QKV scatter. EPI 1: out_f16 = res_f32 + acc. EPI 2: out_f32 = res_f16 + acc.
template <int BM, int BN, int EPI>
__global__ __launch_bounds__(256) void gemm_k(const _Float16* __restrict__ A,
                                              const _Float16* __restrict__ Bt,
                                              int mtiles,
                                              _Float16* __restrict__ e_q,
                                              _Float16* __restrict__ e_k,
                                              _Float16* __restrict__ e_v,
                                              float* __restrict__ e_present,
                                              const void* __restrict__ e_resv,
                                              void* __restrict__ e_outv) {
  constexpr int FM = BM / 32, FN = BN / 32;
  __shared__ __align__(16) char smem[2 * BM * 128 + 2 * BN * 128];
  char* Bbase = smem + 2 * BM * 128;
  const int tid = threadIdx.x, l = tid & 63, w = tid >> 6;
  const int wm = w >> 1, wn = w & 1;
  const int bm = blockIdx.x % mtiles, bn = blockIdx.x / mtiles;
  const long m0 = (long)bm * BM, n0 = (long)bn * BN;

  f32x4 acc[FM][FN];
#pragma unroll
  for (int i = 0; i < FM; ++i)
#pragma unroll
    for (int j = 0; j < FN; ++j) acc[i][j] = (f32x4){0.f, 0.f, 0.f, 0.f};

  auto stage = [&](int b, int kt) {
#pragma unroll
    for (int i = 0; i < FM; ++i) {
      const int cid = i * 256 + tid, row = cid >> 3, u = cid & 7;
      glds16(A + (m0 + row) * 1024 + kt * 64 + ((u ^ (row & 7)) << 3),
             smem + b * BM * 128 + i * 4096 + w * 1024);
    }
#pragma unroll
    for (int i = 0; i < FN; ++i) {
      const int cid = i * 256 + tid, row = cid >> 3, u = cid & 7;
      glds16(Bt + (n0 + row) * 1024 + kt * 64 + ((u ^ (row & 7)) << 3),
             Bbase + b * BN * 128 + i * 4096 + w * 1024);
    }
  };

  stage(0, 0);
  __syncthreads();
  for (int kt = 0; kt < 16; ++kt) {
    const int cur = kt & 1;
    if (kt < 15) stage(cur ^ 1, kt + 1);
    const char* As = smem + cur * BM * 128;
    const char* Bs = Bbase + cur * BN * 128;
    __builtin_amdgcn_s_setprio(1);
#pragma unroll
    for (int k2 = 0; k2 < 2; ++k2) {
      const int sl = k2 * 4 + (l >> 4);
      half8 bfr[FN];
#pragma unroll
      for (int fn = 0; fn < FN; ++fn) {
        const int rn = wn * (BN / 2) + fn * 16 + (l & 15);
        bfr[fn] = *(const half8*)(Bs + rn * 128 + ((sl ^ (rn & 7)) << 4));
      }
#pragma unroll
      for (int fm = 0; fm < FM; ++fm) {
        const int rm = wm * (BM / 2) + fm * 16 + (l & 15);
        const half8 afr = *(const half8*)(As + rm * 128 + ((sl ^ (rm & 7)) << 4));
#pragma unroll
        for (int fn = 0; fn < FN; ++fn)
          acc[fm][fn] = __builtin_amdgcn_mfma_f32_16x16x32_f16(afr, bfr[fn], acc[fm][fn], 0, 0, 0);
      }
    }
    __builtin_amdgcn_s_setprio(0);
    __syncthreads();
  }
#pragma unroll
  for (int fm = 0; fm < FM; ++fm) {
#pragma unroll
    for (int fn = 0; fn < FN; ++fn) {
#pragma unroll
      for (int r = 0; r < 4; ++r) {
        const long row = m0 + wm * (BM / 2) + fm * 16 + (l >> 4) * 4 + r;
        const long col = n0 + wn * (BN / 2) + fn * 16 + (l & 15);
        const float v = acc[fm][fn][r];
        if constexpr (EPI == 0) {
          const int b = (int)(row >> 10), t = (int)(row & 1023);
          const int sec = (int)(col >> 10), h = ((int)col >> 6) & 15, hd = (int)col & 63;
          const long bh = b * 16 + h;
          if (sec == 0) {
            e_q[(bh * 1024 + t) * 64 + hd] = (_Float16)v;
          } else if (sec == 1) {
            e_present[(((long)(b * 2) * 16 + h) * 1024 + t) * 64 + hd] = v;
            e_k[(bh * 2048 + 1024 + t) * 64 + hd] = (_Float16)v;
          } else {
            e_present[(((long)(b * 2 + 1) * 16 + h) * 1024 + t) * 64 + hd] = v;
            e_v[(bh * 1024 + t) * 64 + hd] = (_Float16)v;
          }
        } else if constexpr (EPI == 1) {
          ((_Float16*)e_outv)[row * 1024 + col] =
              (_Float16)(((const float*)e_resv)[row * 1024 + col] + v);
        } else {
          ((float*)e_outv)[row * 1024 + col] =
              (float)((const _Float16*)e_resv)[row * 1024 + col] + v;
        }
      }
    }
  }
}

// ---------------------------------------------------------------------------
// Fused attention (r8-exact). Block = (b,h,q-tile-of-64); wave owns 16 q-rows.
// Phase 1: 128-col kv chunks, K dbuf in the 32KB region (half the barriers).
// Phase 2: 64-col chunks, K+V dbuf. setprio around MFMA clusters.
// LDS 40 KB -> 4 blocks/CU. Swapped QK^T, no-max softmax, XCD-pinned.
__global__ __launch_bounds__(256, 4) void attn_k(const _Float16* __restrict__ qg,
                                                 const _Float16* __restrict__ kg,
                                                 const _Float16* __restrict__ vtg,
                                                 float* __restrict__ msk,
                                                 _Float16* __restrict__ ah) {
  __shared__ __align__(16) char smem[40960];
  char* ps_all = smem + 32768;
  const int tid = threadIdx.x, l = tid & 63, w = tid >> 6;
  char* psw = ps_all + w * 2048;  // wave-private [16 rows][128B]
  const int lq = l & 15, hi = l >> 4;

  // XCD-pinned decode: bh's 16 q-tiles all land on XCD (bh & 7)
  const int x = blockIdx.x & 7, g = blockIdx.x >> 3;
  const int bh = (g & 7) * 8 + x;
  const int qt = 15 - (g >> 3);  // heavy tiles first
  const int r0 = qt << 6;
  const int rowg0 = r0 + w * 16;  // this wave's first global q-row

  const _Float16* kb = kg + (long)bh * 131072;
  const _Float16* vb = vtg + (long)bh * 131072;
  float* mskb = msk + ((long)bh * 1024 + rowg0) * 2048;

  // Q fragments for this wave's 16 rows (row = lq, k = k2*32 + hi*8)
  half8 qa[2];
  {
    const _Float16* qp = qg + ((long)bh * 1024 + rowg0 + lq) * 64 + hi * 8;
    qa[0] = *(const half8*)qp;
    qa[1] = *(const half8*)(qp + 32);
  }

  constexpr float C1 = 0.125f * 1.44269504088896341f;  // 1/sqrt(64) * log2e
  const int lim = rowg0 + lq + 1024;  // causal: col <= lim for this lane's row

  // ---- phase 1: row sums of 2^(S*C1). 128-col chunks, K dbuf in 2x16KB.
  const int nc1 = (r0 + 1215) >> 7;
  auto stageK128 = [&](int b, int c) {
#pragma unroll
    for (int i = 0; i < 4; ++i) {
      const int cid = i * 256 + tid, row = cid >> 3, u = cid & 7;
      glds16(kb + (long)(c * 128 + row) * 64 + ((u ^ (row & 7)) << 3),
             smem + b * 16384 + i * 4096 + w * 1024);
    }
  };
  float rsum = 0.f;
  stageK128(0, 0);
  __syncthreads();
  for (int c = 0; c < nc1; ++c) {
    const int cur = c & 1;
    if (c + 1 < nc1) stageK128(cur ^ 1, c + 1);
    const char* ks = smem + cur * 16384;
    f32x4 sa[8];
#pragma unroll
    for (int fn = 0; fn < 8; ++fn) sa[fn] = (f32x4){0.f, 0.f, 0.f, 0.f};
    __builtin_amdgcn_s_setprio(1);
#pragma unroll
    for (int k2 = 0; k2 < 2; ++k2) {
      const int sl = k2 * 4 + hi;
      half8 ak[8];
#pragma unroll
      for (int fn = 0; fn < 8; ++fn) {
        const int rn = fn * 16 + lq;
        ak[fn] = *(const half8*)(ks + rn * 128 + ((sl ^ (rn & 7)) << 4));
      }
#pragma unroll
      for (int fn = 0; fn < 8; ++fn)
        sa[fn] = __builtin_amdgcn_mfma_f32_16x16x32_f16(ak[fn], qa[k2], sa[fn], 0, 0, 0);
    }
    __builtin_amdgcn_s_setprio(0);
    if (c < nc1 - 1) {
#pragma unroll
      for (int fn = 0; fn < 8; ++fn)
#pragma unroll
        for (int r = 0; r < 4; ++r) rsum += __builtin_amdgcn_exp2f(sa[fn][r] * C1);
    } else {
#pragma unroll
      for (int fn = 0; fn < 8; ++fn)
#pragma unroll
        for (int r = 0; r < 4; ++r) {
          const int col = c * 128 + fn * 16 + hi * 4 + r;
          const float e = __builtin_amdgcn_exp2f(sa[fn][r] * C1);
          rsum += (col <= lim) ? e : 0.f;
        }
    }
    __syncthreads();
  }
  // combine the 4 lanes (hi=0..3) sharing q-row lq
  rsum += __shfl_xor(rsum, 16, 64);
  rsum += __shfl_xor(rsum, 32, 64);
  const float c2s = -__builtin_amdgcn_logf(rsum);  // -log2(sum)

  // ---- phase 2: 64-col chunks; recompute S, p, msk + P(LDS) + PV
  const int nc = (r0 + 1151) >> 6;
  auto stageK = [&](int b, int c) {
#pragma unroll
    for (int i = 0; i < 2; ++i) {
      const int cid = i * 256 + tid, row = cid >> 3, u = cid & 7;
      glds16(kb + (long)(c * 64 + row) * 64 + ((u ^ (row & 7)) << 3),
             smem + b * 8192 + i * 4096 + w * 1024);
    }
  };
  auto stageV = [&](int b, int c) {
#pragma unroll
    for (int i = 0; i < 2; ++i) {
      const int cid = i * 256 + tid, row = cid >> 3, u = cid & 7;
      glds16(vb + (long)row * 2048 + c * 64 + ((u ^ (row & 7)) << 3),
             smem + 16384 + b * 8192 + i * 4096 + w * 1024);
    }
  };

  f32x4 pv[4];
#pragma unroll
  for (int j = 0; j < 4; ++j) pv[j] = (f32x4){0.f, 0.f, 0.f, 0.f};
  __syncthreads();  // phase-1 LDS reads done before phase-2 staging
  stageK(0, 0);
  stageV(0, 0);
  __syncthreads();
  for (int c = 0; c < nc; ++c) {
    const int cur = c & 1;
    if (c + 1 < nc) {
      stageK(cur ^ 1, c + 1);
      stageV(cur ^ 1, c + 1);
    }
    const char* ks = smem + cur * 8192;
    f32x4 sa[4];
#pragma unroll
    for (int fn = 0; fn < 4; ++fn) sa[fn] = (f32x4){0.f, 0.f, 0.f, 0.f};
    __builtin_amdgcn_s_setprio(1);
#pragma unroll
    for (int k2 = 0; k2 < 2; ++k2) {
      const int sl = k2 * 4 + hi;
      half8 ak[4];
#pragma unroll
      for (int fn = 0; fn < 4; ++fn) {
        const int rn = fn * 16 + lq;
        ak[fn] = *(const half8*)(ks + rn * 128 + ((sl ^ (rn & 7)) << 4));
      }
#pragma unroll
      for (int fn = 0; fn < 4; ++fn)
        sa[fn] = __builtin_amdgcn_mfma_f32_16x16x32_f16(ak[fn], qa[k2], sa[fn], 0, 0, 0);
    }
    __builtin_amdgcn_s_setprio(0);
    const bool bound = (c == nc - 1);
#pragma unroll
    for (int fn = 0; fn < 4; ++fn) {
      float pr[4];
#pragma unroll
      for (int r = 0; r < 4; ++r) {
        float p = __builtin_amdgcn_exp2f(sa[fn][r] * C1 + c2s);
        if (bound) {
          const int col = c * 64 + fn * 16 + hi * 4 + r;
          p = (col <= lim) ? p : 0.f;
        }
        pr[r] = p;
      }
      // msk: 16B store, wave covers 16 rows x 64B per fn
      *(float4*)(mskb + (long)lq * 2048 + c * 64 + fn * 16 + hi * 4) =
          make_float4(pr[0], pr[1], pr[2], pr[3]);
      // P -> LDS f16 (swizzle-consistent with the b128 PV reads)
      const half4v hv = {(_Float16)pr[0], (_Float16)pr[1], (_Float16)pr[2],
                         (_Float16)pr[3]};
      const int bc = fn * 32 + hi * 8;  // byte col in [0,128)
      *(half4v*)(psw + lq * 128 + ((((bc >> 4) ^ (lq & 7)) << 4) | (bc & 15))) = hv;
    }
    __builtin_amdgcn_wave_barrier();
    asm volatile("s_waitcnt lgkmcnt(0)" ::: "memory");
    __builtin_amdgcn_sched_barrier(0);
    // PV: A = this wave's P rows, B = V^T rows from LDS
    const char* vs = smem + 16384 + cur * 8192;
    __builtin_amdgcn_s_setprio(1);
#pragma unroll
    for (int k2p = 0; k2p < 2; ++k2p) {
      const int sl2 = k2p * 4 + hi;
      const half8 pa = *(const half8*)(psw + lq * 128 + ((sl2 ^ (lq & 7)) << 4));
      half8 bv[4];
#pragma unroll
      for (int fn2 = 0; fn2 < 4; ++fn2) {
        const int rd = fn2 * 16 + lq;
        bv[fn2] = *(const half8*)(vs + rd * 128 + ((sl2 ^ (rd & 7)) << 4));
      }
#pragma unroll
      for (int fn2 = 0; fn2 < 4; ++fn2)
        pv[fn2] = __builtin_amdgcn_mfma_f32_16x16x32_f16(pa, bv[fn2], pv[fn2], 0, 0, 0);
    }
    __builtin_amdgcn_s_setprio(0);
    __syncthreads();
  }

  // zero-fill fully-masked tail columns (cols >= nc*64) for this wave's rows
  const int ntail = 512 - (nc << 4);  // float4s per row
  if (ntail > 0) {
    const float4 z4 = make_float4(0.f, 0.f, 0.f, 0.f);
    for (int row = 0; row < 16; ++row)
      for (int i = l; i < ntail; i += 64)
        *(float4*)(mskb + (long)row * 2048 + nc * 64 + i * 4) = z4;
  }

  // attention output rows -> ah (B*T,1024) f16
  const int b_ = bh >> 4, h_ = bh & 15;
  _Float16* ahb = ah + ((long)b_ * 1024 + rowg0) * 1024 + h_ * 64;
#pragma unroll
  for (int fn2 = 0; fn2 < 4; ++fn2)
#pragma unroll
    for (int r = 0; r < 4; ++r)
      ahb[(long)(hi * 4 + r) * 1024 + fn2 * 16 + lq] = (_Float16)pv[fn2][r];
}

// ---------------------------------------------------------------------------
extern "C" void kernel_launch(void* const* d_in, const int* in_sizes, int n_in,
                              void* d_out, int out_size, void* d_ws, size_t ws_size,
                              hipStream_t stream) {
  const float* x = (const float*)d_in[0];
  const float* past = (const float*)d_in[1];
  const float* qkv_wt = (const float*)d_in[2];
  const float* qkv_mt = (const float*)d_in[3];
  const float* merge_wt = (const float*)d_in[4];
  const float* merge_mt = (const float*)d_in[5];
  const float* ln1_wt = (const float*)d_in[6];
  const float* ln1_mt = (const float*)d_in[7];
  const float* g1 = (const float*)d_in[8];
  const float* b1 = (const float*)d_in[9];
  const float* g2 = (const float*)d_in[10];
  const float* b2 = (const float*)d_in[11];

  float* out = (float*)d_out;
  float* o_xm = out;                       // (4,1024,1024)
  float* o_present = out + 4194304;        // (4,2,16,1024,64)
  float* o_msk = out + 4194304 + 8388608;  // (4,16,1024,2048)

  char* ws = (char*)d_ws;
  _Float16* wq_t = (_Float16*)(ws + 0);         // 3072x1024 f16
  _Float16* wm_t = (_Float16*)(ws + 6291456);   // 1024x1024 f16
  _Float16* wl_t = (_Float16*)(ws + 8388608);   // 1024x1024 f16
  _Float16* xn   = (_Float16*)(ws + 10485760);  // 4096x1024 f16
  _Float16* qws  = (_Float16*)(ws + 18874368);  // (4,16,1024,64)
  _Float16* kful = (_Float16*)(ws + 27262976);  // (4,16,2048,64)
  _Float16* vnew = (_Float16*)(ws + 44040192);  // (4,16,1024,64)
  _Float16* vt   = (_Float16*)(ws + 52428800);  // (4,16,64,2048)
  _Float16* ah   = (_Float16*)(ws + 69206016);  // 4096x1024 f16
  _Float16* xa   = (_Float16*)(ws + 77594624);  // 4096x1024 f16 (residual)

  prep_all<<<6400, 256, 0, stream>>>(qkv_wt, qkv_mt, merge_wt, merge_mt, ln1_wt,
                                     ln1_mt, wq_t, wm_t, wl_t, past, kful, vt);
  ln_k<0><<<4096, 256, 0, stream>>>(x, g1, b1, xn);
  gemm_k<128, 128, 0><<<768, 256, 0, stream>>>(xn, wq_t, 32, qws, kful, vnew,
                                               o_present, nullptr, nullptr);
  kv_late<<<1024, 256, 0, stream>>>(vnew, vt);
  attn_k<<<1024, 256, 0, stream>>>(qws, kful, vt, o_msk, ah);
  gemm_k<64, 128, 1><<<512, 256, 0, stream>>>(ah, wm_t, 64, nullptr, nullptr,
                                              nullptr, nullptr, x, xa);
  ln_k<1><<<4096, 256, 0, stream>>>(xa, g2, b2, xn);
  gemm_k<64, 128, 2><<<512, 256, 0, stream>>>(xn, wl_t, 64, nullptr, nullptr,
                                              nullptr, nullptr, xa, o_xm);
}

// Round 14
// 287.585 us; speedup vs baseline: 1.0661x; 1.0066x over previous
//
#include <hip/hip_runtime.h>
#include <hip/hip_bf16.h>

typedef _Float16 half8 __attribute__((ext_vector_type(8)));
typedef _Float16 half4v __attribute__((ext_vector_type(4)));
typedef float f32x4 __attribute__((ext_vector_type(4)));

#define DEV static __device__ __forceinline__

// Problem constants: B=4, T=1024, D=1024, H=16, HD=64, TP=1024, SKV=2048

typedef __attribute__((address_space(1))) const unsigned int* gas_p;
typedef __attribute__((address_space(3))) unsigned int* las_p;
DEV void glds16(const void* g, void* s) {
  __builtin_amdgcn_global_load_lds((gas_p)g, (las_p)s, 16, 0, 0);
}

// ---------------------------------------------------------------------------
// Fused front-end: weight prep + past-K conversion + past-V transpose + LN1.
// blocks [0,768): qkv w prep (N=3072); [768,1024): merge; [1024,1280): ln1 w;
// blocks [1280,5376): past k fp32 -> kful rows 0..1023 f16;
// blocks [5376,6400): v^T from past v (k0 < 1024);
// blocks [6400,10496): LayerNorm1 rows (fp32 x -> f16 xn).
__global__ __launch_bounds__(256) void prep_all(const float* __restrict__ qkv_wt,
                                                const float* __restrict__ qkv_mt,
                                                const float* __restrict__ mg_wt,
                                                const float* __restrict__ mg_mt,
                                                const float* __restrict__ l1_wt,
                                                const float* __restrict__ l1_mt,
                                                _Float16* __restrict__ wq,
                                                _Float16* __restrict__ wm,
                                                _Float16* __restrict__ wl,
                                                const float* __restrict__ past,
                                                _Float16* __restrict__ kf,
                                                _Float16* __restrict__ vt,
                                                const float* __restrict__ x,
                                                const float* __restrict__ g1,
                                                const float* __restrict__ b1,
                                                _Float16* __restrict__ xn) {
  __shared__ float tile[64][65];
  if (blockIdx.x >= 6400) {  // ---- LN1 rows
    float* red = &tile[0][0];
    const int row = blockIdx.x - 6400, tid = threadIdx.x, l = tid & 63, w = tid >> 6;
    float4 v = *(const float4*)(x + (long)row * 1024 + tid * 4);
    float s = v.x + v.y + v.z + v.w;
#pragma unroll
    for (int o = 32; o > 0; o >>= 1) s += __shfl_down(s, o, 64);
    if (l == 0) red[w] = s;
    __syncthreads();
    const float mu = (red[0] + red[1] + red[2] + red[3]) * (1.f / 1024.f);
    float dx = v.x - mu, dy = v.y - mu, dz = v.z - mu, dw = v.w - mu;
    float ss = dx * dx + dy * dy + dz * dz + dw * dw;
#pragma unroll
    for (int o = 32; o > 0; o >>= 1) ss += __shfl_down(ss, o, 64);
    __syncthreads();
    if (l == 0) red[w] = ss;
    __syncthreads();
    const float var = (red[0] + red[1] + red[2] + red[3]) * (1.f / 1024.f);
    const float rs = rsqrtf(var + 1e-3f);
    float4 gv = *(const float4*)(g1 + tid * 4);
    float4 bv = *(const float4*)(b1 + tid * 4);
    half4v o = {(_Float16)(dx * rs * gv.x + bv.x), (_Float16)(dy * rs * gv.y + bv.y),
                (_Float16)(dz * rs * gv.z + bv.z), (_Float16)(dw * rs * gv.w + bv.w)};
    *(half4v*)(xn + (long)row * 1024 + tid * 4) = o;
    return;
  }
  if (blockIdx.x >= 1280 && blockIdx.x < 5376) {  // ---- past-K conversion
    const long e = ((long)(blockIdx.x - 1280) * 256 + threadIdx.x) * 4;
    const int b = (int)(e >> 20);
    const int rem = (int)(e & 1048575);
    float4 v = *(const float4*)(past + (long)b * 2097152 + rem);
    half4v o = {(_Float16)v.x, (_Float16)v.y, (_Float16)v.z, (_Float16)v.w};
    const int h = rem >> 16, td = rem & 65535;
    *(half4v*)(kf + (long)(b * 16 + h) * 131072 + td) = o;
    return;
  }
  if (blockIdx.x >= 5376) {  // ---- past-V transpose (k0 < 1024)
    const int bid = blockIdx.x - 5376;
    const int bh = bid >> 4, kt = bid & 15;
    const int b = bh >> 4, h = bh & 15;
    const int k0 = kt << 6;
    const int t = threadIdx.x, r = t >> 2, c0 = (t & 3) << 4;
    const float* src = past + (((long)(b * 2 + 1) * 16 + h) * 1024 + (k0 + r)) * 64 + c0;
#pragma unroll
    for (int j = 0; j < 16; j += 4) {
      float4 v = *(const float4*)(src + j);
      tile[r][c0 + j + 0] = v.x;
      tile[r][c0 + j + 1] = v.y;
      tile[r][c0 + j + 2] = v.z;
      tile[r][c0 + j + 3] = v.w;
    }
    __syncthreads();
    half8 o0, o1;
#pragma unroll
    for (int j = 0; j < 8; ++j) {
      o0[j] = (_Float16)tile[c0 + j][r];
      o1[j] = (_Float16)tile[c0 + 8 + j][r];
    }
    _Float16* dst = vt + ((long)bh * 64 + r) * 2048 + k0 + c0;
    *(half8*)dst = o0;
    *(half8*)(dst + 8) = o1;
    return;
  }
  // ---- weight prep path
  const float *wt, *mt;
  _Float16* out;
  int N, bid;
  if (blockIdx.x < 768) {
    wt = qkv_wt; mt = qkv_mt; out = wq; N = 3072; bid = blockIdx.x;
  } else if (blockIdx.x < 1024) {
    wt = mg_wt; mt = mg_mt; out = wm; N = 1024; bid = blockIdx.x - 768;
  } else {
    wt = l1_wt; mt = l1_mt; out = wl; N = 1024; bid = blockIdx.x - 1024;
  }
  const int ntiles = N >> 6;
  const int nt = bid % ntiles, kt = bid / ntiles;
  const int k0 = kt << 6, n0 = nt << 6;
  const int t = threadIdx.x, r = t >> 2, c0 = (t & 3) << 4;
  const long ibase = (long)(k0 + r) * N + n0 + c0;
#pragma unroll
  for (int j = 0; j < 16; j += 4) {
    float4 a = *(const float4*)(wt + ibase + j);
    float4 b = *(const float4*)(mt + ibase + j);
    tile[r][c0 + j + 0] = tanhf(a.x) / (1.f + __expf(-b.x));
    tile[r][c0 + j + 1] = tanhf(a.y) / (1.f + __expf(-b.y));
    tile[r][c0 + j + 2] = tanhf(a.z) / (1.f + __expf(-b.z));
    tile[r][c0 + j + 3] = tanhf(a.w) / (1.f + __expf(-b.w));
  }
  __syncthreads();
  half8 o0, o1;
#pragma unroll
  for (int j = 0; j < 8; ++j) {
    o0[j] = (_Float16)tile[c0 + j][r];
    o1[j] = (_Float16)tile[c0 + 8 + j][r];
  }
  _Float16* dst = out + (long)(n0 + r) * 1024 + k0 + c0;
  *(half8*)dst = o0;
  *(half8*)(dst + 8) = o1;
}

// ---------------------------------------------------------------------------
// Post-QKV v^T tail: k0 >= 1024 quarter of v^T, from vnew (GEMM output).
__global__ __launch_bounds__(256) void kv_late(const _Float16* __restrict__ vnew,
                                               _Float16* __restrict__ vt) {
  __shared__ float tile[64][65];
  const int bid = blockIdx.x;
  const int bh = bid >> 4, kt = 16 + (bid & 15);
  const int k0 = kt << 6;
  const int t = threadIdx.x, r = t >> 2, c0 = (t & 3) << 4;
  const _Float16* src = vnew + ((long)bh * 1024 + (k0 - 1024 + r)) * 64 + c0;
  half8 a = *(const half8*)src;
  half8 bq = *(const half8*)(src + 8);
#pragma unroll
  for (int j = 0; j < 8; ++j) {
    tile[r][c0 + j] = (float)a[j];
    tile[r][c0 + 8 + j] = (float)bq[j];
  }
  __syncthreads();
  half8 o0, o1;
#pragma unroll
  for (int j = 0; j < 8; ++j) {
    o0[j] = (_Float16)tile[c0 + j][r];
    o1[j] = (_Float16)tile[c0 + 8 + j][r];
  }
  _Float16* dst = vt + ((long)bh * 64 + r) * 2048 + k0 + c0;
  *(half8*)dst = o0;
  *(half8*)(dst + 8) = o1;
}

// ---------------------------------------------------------------------------
// LayerNorm row kernel (f16 in -> f16 out), used for LN2.
__global__ __launch_bounds__(256) void ln_k(const _Float16* __restrict__ xin,
                                            const float* __restrict__ g,
                                            const float* __restrict__ be,
                                            _Float16* __restrict__ out) {
  __shared__ float red[4];
  const int row = blockIdx.x, tid = threadIdx.x, l = tid & 63, w = tid >> 6;
  half4v v = *(const half4v*)(xin + (long)row * 1024 + tid * 4);
  float v0 = (float)v[0], v1 = (float)v[1], v2 = (float)v[2], v3 = (float)v[3];
  float s = v0 + v1 + v2 + v3;
#pragma unroll
  for (int o = 32; o > 0; o >>= 1) s += __shfl_down(s, o, 64);
  if (l == 0) red[w] = s;
  __syncthreads();
  const float mu = (red[0] + red[1] + red[2] + red[3]) * (1.f / 1024.f);
  float dx = v0 - mu, dy = v1 - mu, dz = v2 - mu, dw = v3 - mu;
  float ss = dx * dx + dy * dy + dz * dz + dw * dw;
#pragma unroll
  for (int o = 32; o > 0; o >>= 1) ss += __shfl_down(ss, o, 64);
  __syncthreads();
  if (l == 0) red[w] = ss;
  __syncthreads();
  const float var = (red[0] + red[1] + red[2] + red[3]) * (1.f / 1024.f);
  const float rs = rsqrtf(var + 1e-3f);
  float4 gv = *(const float4*)(g + tid * 4);
  float4 bv = *(const float4*)(be + tid * 4);
  half4v o = {(_Float16)(dx * rs * gv.x + bv.x), (_Float16)(dy * rs * gv.y + bv.y),
              (_Float16)(dz * rs * gv.z + bv.z), (_Float16)(dw * rs * gv.w + bv.w)};
  *(half4v*)(out + (long)row * 1024 + tid * 4) = o;
}

// ---------------------------------------------------------------------------
// GEMM BMxBN tile, BK=64, 256 threads (4 waves 2x2), K=1024, glds staging,
// DOUBLE-buffered LDS, 1 barrier per K-step (r8-proven structure).
// EPI 0: QKV scatter. EPI 1: out_f16 = res_f32 + acc. EPI 2: out_f32 = res_f16 + acc.
template <int BM, int BN, int EPI>
__global__ __launch_bounds__(256) void gemm_k(const _Float16* __restrict__ A,
                                              const _Float16* __restrict__ Bt,
                                              int mtiles,
                                              _Float16* __restrict__ e_q,
                                              _Float16* __restrict__ e_k,
                                              _Float16* __restrict__ e_v,
                                              float* __restrict__ e_present,
                                              const void* __restrict__ e_resv,
                                              void* __restrict__ e_outv) {
  constexpr int FM = BM / 32, FN = BN / 32;
  __shared__ __align__(16) char smem[2 * BM * 128 + 2 * BN * 128];
  char* Bbase = smem + 2 * BM * 128;
  const int tid = threadIdx.x, l = tid & 63, w = tid >> 6;
  const int wm = w >> 1, wn = w & 1;
  const int bm = blockIdx.x % mtiles, bn = blockIdx.x / mtiles;
  const long m0 = (long)bm * BM, n0 = (long)bn * BN;

  f32x4 acc[FM][FN];
#pragma unroll
  for (int i = 0; i < FM; ++i)
#pragma unroll
    for (int j = 0; j < FN; ++j) acc[i][j] = (f32x4){0.f, 0.f, 0.f, 0.f};

  auto stage = [&](int b, int kt) {
#pragma unroll
    for (int i = 0; i < FM; ++i) {
      const int cid = i * 256 + tid, row = cid >> 3, u = cid & 7;
      glds16(A + (m0 + row) * 1024 + kt * 64 + ((u ^ (row & 7)) << 3),
             smem + b * BM * 128 + i * 4096 + w * 1024);
    }
#pragma unroll
    for (int i = 0; i < FN; ++i) {
      const int cid = i * 256 + tid, row = cid >> 3, u = cid & 7;
      glds16(Bt + (n0 + row) * 1024 + kt * 64 + ((u ^ (row & 7)) << 3),
             Bbase + b * BN * 128 + i * 4096 + w * 1024);
    }
  };

  stage(0, 0);
  __syncthreads();
  for (int kt = 0; kt < 16; ++kt) {
    const int cur = kt & 1;
    if (kt < 15) stage(cur ^ 1, kt + 1);
    const char* As = smem + cur * BM * 128;
    const char* Bs = Bbase + cur * BN * 128;
    __builtin_amdgcn_s_setprio(1);
#pragma unroll
    for (int k2 = 0; k2 < 2; ++k2) {
      const int sl = k2 * 4 + (l >> 4);
      half8 bfr[FN];
#pragma unroll
      for (int fn = 0; fn < FN; ++fn) {
        const int rn = wn * (BN / 2) + fn * 16 + (l & 15);
        bfr[fn] = *(const half8*)(Bs + rn * 128 + ((sl ^ (rn & 7)) << 4));
      }
#pragma unroll
      for (int fm = 0; fm < FM; ++fm) {
        const int rm = wm * (BM / 2) + fm * 16 + (l & 15);
        const half8 afr = *(const half8*)(As + rm * 128 + ((sl ^ (rm & 7)) << 4));
#pragma unroll
        for (int fn = 0; fn < FN; ++fn)
          acc[fm][fn] = __builtin_amdgcn_mfma_f32_16x16x32_f16(afr, bfr[fn], acc[fm][fn], 0, 0, 0);
      }
    }
    __builtin_amdgcn_s_setprio(0);
    __syncthreads();
  }
#pragma unroll
  for (int fm = 0; fm < FM; ++fm) {
#pragma unroll
    for (int fn = 0; fn < FN; ++fn) {
#pragma unroll
      for (int r = 0; r < 4; ++r) {
        const long row = m0 + wm * (BM / 2) + fm * 16 + (l >> 4) * 4 + r;
        const long col = n0 + wn * (BN / 2) + fn * 16 + (l & 15);
        const float v = acc[fm][fn][r];
        if constexpr (EPI == 0) {
          const int b = (int)(row >> 10), t = (int)(row & 1023);
          const int sec = (int)(col >> 10), h = ((int)col >> 6) & 15, hd = (int)col & 63;
          const long bh = b * 16 + h;
          if (sec == 0) {
            e_q[(bh * 1024 + t) * 64 + hd] = (_Float16)v;
          } else if (sec == 1) {
            e_present[(((long)(b * 2) * 16 + h) * 1024 + t) * 64 + hd] = v;
            e_k[(bh * 2048 + 1024 + t) * 64 + hd] = (_Float16)v;
          } else {
            e_present[(((long)(b * 2 + 1) * 16 + h) * 1024 + t) * 64 + hd] = v;
            e_v[(bh * 1024 + t) * 64 + hd] = (_Float16)v;
          }
        } else if constexpr (EPI == 1) {
          ((_Float16*)e_outv)[row * 1024 + col] =
              (_Float16)(((const float*)e_resv)[row * 1024 + col] + v);
        } else {
          ((float*)e_outv)[row * 1024 + col] =
              (float)((const _Float16*)e_resv)[row * 1024 + col] + v;
        }
      }
    }
  }
}

// ---------------------------------------------------------------------------
// Fused attention (r8-exact). Block = (b,h,q-tile-of-64); wave owns 16 q-rows.
// Phase 1: 128-col kv chunks, K dbuf in the 32KB region (half the barriers).
// Phase 2: 64-col chunks, K+V dbuf. setprio around MFMA clusters.
// LDS 40 KB -> 4 blocks/CU. Swapped QK^T, no-max softmax, XCD-pinned.
__global__ __launch_bounds__(256, 4) void attn_k(const _Float16* __restrict__ qg,
                                                 const _Float16* __restrict__ kg,
                                                 const _Float16* __restrict__ vtg,
                                                 float* __restrict__ msk,
                                                 _Float16* __restrict__ ah) {
  __shared__ __align__(16) char smem[40960];
  char* ps_all = smem + 32768;
  const int tid = threadIdx.x, l = tid & 63, w = tid >> 6;
  char* psw = ps_all + w * 2048;  // wave-private [16 rows][128B]
  const int lq = l & 15, hi = l >> 4;

  // XCD-pinned decode: bh's 16 q-tiles all land on XCD (bh & 7)
  const int x = blockIdx.x & 7, g = blockIdx.x >> 3;
  const int bh = (g & 7) * 8 + x;
  const int qt = 15 - (g >> 3);  // heavy tiles first
  const int r0 = qt << 6;
  const int rowg0 = r0 + w * 16;  // this wave's first global q-row

  const _Float16* kb = kg + (long)bh * 131072;
  const _Float16* vb = vtg + (long)bh * 131072;
  float* mskb = msk + ((long)bh * 1024 + rowg0) * 2048;

  // Q fragments for this wave's 16 rows (row = lq, k = k2*32 + hi*8)
  half8 qa[2];
  {
    const _Float16* qp = qg + ((long)bh * 1024 + rowg0 + lq) * 64 + hi * 8;
    qa[0] = *(const half8*)qp;
    qa[1] = *(const half8*)(qp + 32);
  }

  constexpr float C1 = 0.125f * 1.44269504088896341f;  // 1/sqrt(64) * log2e
  const int lim = rowg0 + lq + 1024;  // causal: col <= lim for this lane's row

  // ---- phase 1: row sums of 2^(S*C1). 128-col chunks, K dbuf in 2x16KB.
  const int nc1 = (r0 + 1215) >> 7;
  auto stageK128 = [&](int b, int c) {
#pragma unroll
    for (int i = 0; i < 4; ++i) {
      const int cid = i * 256 + tid, row = cid >> 3, u = cid & 7;
      glds16(kb + (long)(c * 128 + row) * 64 + ((u ^ (row & 7)) << 3),
             smem + b * 16384 + i * 4096 + w * 1024);
    }
  };
  float rsum = 0.f;
  stageK128(0, 0);
  __syncthreads();
  for (int c = 0; c < nc1; ++c) {
    const int cur = c & 1;
    if (c + 1 < nc1) stageK128(cur ^ 1, c + 1);
    const char* ks = smem + cur * 16384;
    f32x4 sa[8];
#pragma unroll
    for (int fn = 0; fn < 8; ++fn) sa[fn] = (f32x4){0.f, 0.f, 0.f, 0.f};
    __builtin_amdgcn_s_setprio(1);
#pragma unroll
    for (int k2 = 0; k2 < 2; ++k2) {
      const int sl = k2 * 4 + hi;
      half8 ak[8];
#pragma unroll
      for (int fn = 0; fn < 8; ++fn) {
        const int rn = fn * 16 + lq;
        ak[fn] = *(const half8*)(ks + rn * 128 + ((sl ^ (rn & 7)) << 4));
      }
#pragma unroll
      for (int fn = 0; fn < 8; ++fn)
        sa[fn] = __builtin_amdgcn_mfma_f32_16x16x32_f16(ak[fn], qa[k2], sa[fn], 0, 0, 0);
    }
    __builtin_amdgcn_s_setprio(0);
    if (c < nc1 - 1) {
#pragma unroll
      for (int fn = 0; fn < 8; ++fn)
#pragma unroll
        for (int r = 0; r < 4; ++r) rsum += __builtin_amdgcn_exp2f(sa[fn][r] * C1);
    } else {
#pragma unroll
      for (int fn = 0; fn < 8; ++fn)
#pragma unroll
        for (int r = 0; r < 4; ++r) {
          const int col = c * 128 + fn * 16 + hi * 4 + r;
          const float e = __builtin_amdgcn_exp2f(sa[fn][r] * C1);
          rsum += (col <= lim) ? e : 0.f;
        }
    }
    __syncthreads();
  }
  // combine the 4 lanes (hi=0..3) sharing q-row lq
  rsum += __shfl_xor(rsum, 16, 64);
  rsum += __shfl_xor(rsum, 32, 64);
  const float c2s = -__builtin_amdgcn_logf(rsum);  // -log2(sum)

  // ---- phase 2: 64-col chunks; recompute S, p, msk + P(LDS) + PV
  const int nc = (r0 + 1151) >> 6;
  auto stageK = [&](int b, int c) {
#pragma unroll
    for (int i = 0; i < 2; ++i) {
      const int cid = i * 256 + tid, row = cid >> 3, u = cid & 7;
      glds16(kb + (long)(c * 64 + row) * 64 + ((u ^ (row & 7)) << 3),
             smem + b * 8192 + i * 4096 + w * 1024);
    }
  };
  auto stageV = [&](int b, int c) {
#pragma unroll
    for (int i = 0; i < 2; ++i) {
      const int cid = i * 256 + tid, row = cid >> 3, u = cid & 7;
      glds16(vb + (long)row * 2048 + c * 64 + ((u ^ (row & 7)) << 3),
             smem + 16384 + b * 8192 + i * 4096 + w * 1024);
    }
  };

  f32x4 pv[4];
#pragma unroll
  for (int j = 0; j < 4; ++j) pv[j] = (f32x4){0.f, 0.f, 0.f, 0.f};
  __syncthreads();  // phase-1 LDS reads done before phase-2 staging
  stageK(0, 0);
  stageV(0, 0);
  __syncthreads();
  for (int c = 0; c < nc; ++c) {
    const int cur = c & 1;
    if (c + 1 < nc) {
      stageK(cur ^ 1, c + 1);
      stageV(cur ^ 1, c + 1);
    }
    const char* ks = smem + cur * 8192;
    f32x4 sa[4];
#pragma unroll
    for (int fn = 0; fn < 4; ++fn) sa[fn] = (f32x4){0.f, 0.f, 0.f, 0.f};
    __builtin_amdgcn_s_setprio(1);
#pragma unroll
    for (int k2 = 0; k2 < 2; ++k2) {
      const int sl = k2 * 4 + hi;
      half8 ak[4];
#pragma unroll
      for (int fn = 0; fn < 4; ++fn) {
        const int rn = fn * 16 + lq;
        ak[fn] = *(const half8*)(ks + rn * 128 + ((sl ^ (rn & 7)) << 4));
      }
#pragma unroll
      for (int fn = 0; fn < 4; ++fn)
        sa[fn] = __builtin_amdgcn_mfma_f32_16x16x32_f16(ak[fn], qa[k2], sa[fn], 0, 0, 0);
    }
    __builtin_amdgcn_s_setprio(0);
    const bool bound = (c == nc - 1);
#pragma unroll
    for (int fn = 0; fn < 4; ++fn) {
      float pr[4];
#pragma unroll
      for (int r = 0; r < 4; ++r) {
        float p = __builtin_amdgcn_exp2f(sa[fn][r] * C1 + c2s);
        if (bound) {
          const int col = c * 64 + fn * 16 + hi * 4 + r;
          p = (col <= lim) ? p : 0.f;
        }
        pr[r] = p;
      }
      // msk: 16B store, wave covers 16 rows x 64B per fn
      *(float4*)(mskb + (long)lq * 2048 + c * 64 + fn * 16 + hi * 4) =
          make_float4(pr[0], pr[1], pr[2], pr[3]);
      // P -> LDS f16 (swizzle-consistent with the b128 PV reads)
      const half4v hv = {(_Float16)pr[0], (_Float16)pr[1], (_Float16)pr[2],
                         (_Float16)pr[3]};
      const int bc = fn * 32 + hi * 8;  // byte col in [0,128)
      *(half4v*)(psw + lq * 128 + ((((bc >> 4) ^ (lq & 7)) << 4) | (bc & 15))) = hv;
    }
    __builtin_amdgcn_wave_barrier();
    asm volatile("s_waitcnt lgkmcnt(0)" ::: "memory");
    __builtin_amdgcn_sched_barrier(0);
    // PV: A = this wave's P rows, B = V^T rows from LDS
    const char* vs = smem + 16384 + cur * 8192;
    __builtin_amdgcn_s_setprio(1);
#pragma unroll
    for (int k2p = 0; k2p < 2; ++k2p) {
      const int sl2 = k2p * 4 + hi;
      const half8 pa = *(const half8*)(psw + lq * 128 + ((sl2 ^ (lq & 7)) << 4));
      half8 bv[4];
#pragma unroll
      for (int fn2 = 0; fn2 < 4; ++fn2) {
        const int rd = fn2 * 16 + lq;
        bv[fn2] = *(const half8*)(vs + rd * 128 + ((sl2 ^ (rd & 7)) << 4));
      }
#pragma unroll
      for (int fn2 = 0; fn2 < 4; ++fn2)
        pv[fn2] = __builtin_amdgcn_mfma_f32_16x16x32_f16(pa, bv[fn2], pv[fn2], 0, 0, 0);
    }
    __builtin_amdgcn_s_setprio(0);
    __syncthreads();
  }

  // zero-fill fully-masked tail columns (cols >= nc*64) for this wave's rows
  const int ntail = 512 - (nc << 4);  // float4s per row
  if (ntail > 0) {
    const float4 z4 = make_float4(0.f, 0.f, 0.f, 0.f);
    for (int row = 0; row < 16; ++row)
      for (int i = l; i < ntail; i += 64)
        *(float4*)(mskb + (long)row * 2048 + nc * 64 + i * 4) = z4;
  }

  // attention output rows -> ah (B*T,1024) f16
  const int b_ = bh >> 4, h_ = bh & 15;
  _Float16* ahb = ah + ((long)b_ * 1024 + rowg0) * 1024 + h_ * 64;
#pragma unroll
  for (int fn2 = 0; fn2 < 4; ++fn2)
#pragma unroll
    for (int r = 0; r < 4; ++r)
      ahb[(long)(hi * 4 + r) * 1024 + fn2 * 16 + lq] = (_Float16)pv[fn2][r];
}

// ---------------------------------------------------------------------------
extern "C" void kernel_launch(void* const* d_in, const int* in_sizes, int n_in,
                              void* d_out, int out_size, void* d_ws, size_t ws_size,
                              hipStream_t stream) {
  const float* x = (const float*)d_in[0];
  const float* past = (const float*)d_in[1];
  const float* qkv_wt = (const float*)d_in[2];
  const float* qkv_mt = (const float*)d_in[3];
  const float* merge_wt = (const float*)d_in[4];
  const float* merge_mt = (const float*)d_in[5];
  const float* ln1_wt = (const float*)d_in[6];
  const float* ln1_mt = (const float*)d_in[7];
  const float* g1 = (const float*)d_in[8];
  const float* b1 = (const float*)d_in[9];
  const float* g2 = (const float*)d_in[10];
  const float* b2 = (const float*)d_in[11];

  float* out = (float*)d_out;
  float* o_xm = out;                       // (4,1024,1024)
  float* o_present = out + 4194304;        // (4,2,16,1024,64)
  float* o_msk = out + 4194304 + 8388608;  // (4,16,1024,2048)

  char* ws = (char*)d_ws;
  _Float16* wq_t = (_Float16*)(ws + 0);         // 3072x1024 f16
  _Float16* wm_t = (_Float16*)(ws + 6291456);   // 1024x1024 f16
  _Float16* wl_t = (_Float16*)(ws + 8388608);   // 1024x1024 f16
  _Float16* xn   = (_Float16*)(ws + 10485760);  // 4096x1024 f16
  _Float16* qws  = (_Float16*)(ws + 18874368);  // (4,16,1024,64)
  _Float16* kful = (_Float16*)(ws + 27262976);  // (4,16,2048,64)
  _Float16* vnew = (_Float16*)(ws + 44040192);  // (4,16,1024,64)
  _Float16* vt   = (_Float16*)(ws + 52428800);  // (4,16,64,2048)
  _Float16* ah   = (_Float16*)(ws + 69206016);  // 4096x1024 f16
  _Float16* xa   = (_Float16*)(ws + 77594624);  // 4096x1024 f16 (residual)

  prep_all<<<10496, 256, 0, stream>>>(qkv_wt, qkv_mt, merge_wt, merge_mt, ln1_wt,
                                      ln1_mt, wq_t, wm_t, wl_t, past, kful, vt,
                                      x, g1, b1, xn);
  gemm_k<128, 128, 0><<<768, 256, 0, stream>>>(xn, wq_t, 32, qws, kful, vnew,
                                               o_present, nullptr, nullptr);
  kv_late<<<1024, 256, 0, stream>>>(vnew, vt);
  attn_k<<<1024, 256, 0, stream>>>(qws, kful, vt, o_msk, ah);
  gemm_k<64, 128, 1><<<512, 256, 0, stream>>>(ah, wm_t, 64, nullptr, nullptr,
                                              nullptr, nullptr, x, xa);
  ln_k<<<4096, 256, 0, stream>>>(xa, g2, b2, xn);
  gemm_k<64, 128, 2><<<512, 256, 0, stream>>>(xn, wl_t, 64, nullptr, nullptr,
                                              nullptr, nullptr, xa, o_xm);
}